// Round 5
// baseline (334.984 us; speedup 1.0000x reference)
//
#include <hip/hip_runtime.h>

#define N_NODES 20000
#define FDIM 512
#define SSZ 6
#define NCOPY 8

typedef __attribute__((ext_vector_type(8))) short bf16x8;
typedef __attribute__((ext_vector_type(4))) float f32x4;
typedef __attribute__((ext_vector_type(8))) unsigned short u16x8;

static __device__ __forceinline__ unsigned short f2bf(float f) {
    unsigned int u = __float_as_uint(f);
    unsigned int r = (u + 0x7fffu + ((u >> 16) & 1u)) >> 16;
    return (unsigned short)r;
}
static __device__ __forceinline__ float bf2f(unsigned short u) {
    return __uint_as_float(((unsigned int)u) << 16);
}

// ---------------------------------------------------------------------------
// K0: fused prep.
//  blocks [0,5000)      : x -> bf16
//  blocks [5000,5512)   : W^T bf16
//  blocks [5512,5591)   : per-node unitary coefficients (12 floats/node)
//  blocks [5591,5599)   : zero sums[8*2048]
// ---------------------------------------------------------------------------
__global__ __launch_bounds__(256) void conv_all(
    const float* __restrict__ x, const float* __restrict__ Wre,
    const float* __restrict__ Wim, const int* __restrict__ sub_adj,
    unsigned short* __restrict__ xb, unsigned short* __restrict__ wt,
    float* __restrict__ coef, float* __restrict__ sums)
{
    const int blk = blockIdx.x;
    const int tid = threadIdx.x;
    if (blk < 5000) {
        const size_t i = ((size_t)blk * 256 + tid) * 8;
        const float4 a = *(const float4*)(x + i);
        const float4 b = *(const float4*)(x + i + 4);
        u16x8 o;
        o[0] = f2bf(a.x); o[1] = f2bf(a.y); o[2] = f2bf(a.z); o[3] = f2bf(a.w);
        o[4] = f2bf(b.x); o[5] = f2bf(b.y); o[6] = f2bf(b.z); o[7] = f2bf(b.w);
        *(u16x8*)(xb + i) = o;
    } else if (blk < 5512) {
        __shared__ float tile[32][33];
        const int bidx = blk - 5000;
        const int z = bidx >> 8;
        const int rem = bidx & 255;
        const int k0 = (rem & 15) * 32;
        const int n0 = (rem >> 4) * 32;
        const float* W = z ? Wim : Wre;
        const int tx = tid & 31, ty = tid >> 5;
#pragma unroll
        for (int i = 0; i < 4; ++i)
            tile[ty + i * 8][tx] = W[(size_t)(k0 + ty + i * 8) * FDIM + n0 + tx];
        __syncthreads();
        unsigned short* wtb = wt + (size_t)z * FDIM * FDIM;
#pragma unroll
        for (int i = 0; i < 4; ++i)
            wtb[(size_t)(n0 + ty + i * 8) * FDIM + k0 + tx] = f2bf(tile[tx][ty + i * 8]);
    } else if (blk < 5591) {
        const int c = (blk - 5512) * 256 + tid;
        if (c < N_NODES) {
            const int* sa = sub_adj + (size_t)c * (SSZ * SSZ);
            float A[SSZ][SSZ], deg[SSZ];
#pragma unroll
            for (int s = 0; s < SSZ; ++s) {
                float d = 0.f;
#pragma unroll
                for (int t = 0; t < SSZ; ++t) { float a = (float)sa[s * SSZ + t]; A[s][t] = a; d += a; }
                deg[s] = d;
            }
            float p1[SSZ], p2[SSZ], p3[SSZ], p4[SSZ];
#pragma unroll
            for (int t = 0; t < SSZ; ++t) p1[t] = ((t == 0) ? deg[0] : 0.f) - A[0][t];
#pragma unroll
            for (int t = 0; t < SSZ; ++t) {
                float acc = 0.f;
#pragma unroll
                for (int s = 0; s < SSZ; ++s) acc += p1[s] * (((s == t) ? deg[s] : 0.f) - A[s][t]);
                p2[t] = acc;
            }
#pragma unroll
            for (int t = 0; t < SSZ; ++t) {
                float acc = 0.f;
#pragma unroll
                for (int s = 0; s < SSZ; ++s) acc += p2[s] * (((s == t) ? deg[s] : 0.f) - A[s][t]);
                p3[t] = acc;
            }
#pragma unroll
            for (int t = 0; t < SSZ; ++t) {
                float acc = 0.f;
#pragma unroll
                for (int s = 0; s < SSZ; ++s) acc += p3[s] * (((s == t) ? deg[s] : 0.f) - A[s][t]);
                p4[t] = acc;
            }
#pragma unroll
            for (int t = 0; t < SSZ; ++t) {
                coef[(size_t)c * 12 + t] =
                    ((t == 0) ? 1.f : 0.f) - 3.125e-4f * p2[t] + 1.6276041666666668e-8f * p4[t];
                coef[(size_t)c * 12 + 6 + t] =
                    -0.025f * p1[t] + 2.6041666666666666e-6f * p3[t];
            }
        }
    } else {
        const int base = (blk - 5591) * 2048;
#pragma unroll
        for (int i = 0; i < 8; ++i) sums[base + i * 256 + tid] = 0.f;
    }
}

// ---------------------------------------------------------------------------
// K1: bf16 MFMA GEMM.  y[20000][1024] = xb @ wt^T + bias (bf16 out)
// 64x128 tile, BK=64, 4 waves (2x2, wave tile 32x64), 2x4 frags 16x16x32.
// ---------------------------------------------------------------------------
#define BM 64
#define BN 128
#define BK 64

__global__ __launch_bounds__(256) void gemm_mfma(
    const unsigned short* __restrict__ xb,
    const unsigned short* __restrict__ wt,
    const float* __restrict__ bre, const float* __restrict__ bim,
    unsigned short* __restrict__ y)
{
    __shared__ __align__(16) unsigned short lA[BM * BK];
    __shared__ __align__(16) unsigned short lB[BN * BK];

    const int tid  = threadIdx.x;
    const int wave = tid >> 6;
    const int lane = tid & 63;
    const int rowBase = blockIdx.y * BM;
    const int colBase = blockIdx.x * BN;

    const int wm = (wave >> 1) * 32;
    const int wn = (wave & 1) * 64;

    f32x4 acc[2][4];
#pragma unroll
    for (int i = 0; i < 2; ++i)
#pragma unroll
        for (int j = 0; j < 4; ++j) acc[i][j] = (f32x4){0.f, 0.f, 0.f, 0.f};

    const int srow   = lane >> 3;
    const int schunk = lane & 7;
    const int gchunk = schunk ^ srow;

    const int fm = lane & 15;
    const int kq = lane >> 4;

    for (int k0 = 0; k0 < FDIM; k0 += BK) {
#pragma unroll
        for (int i = 0; i < 2; ++i) {
            const int trow = wave * 16 + i * 8;
            int grow = rowBase + trow + srow;
            if (grow > N_NODES - 1) grow = N_NODES - 1;
            const unsigned short* gp = xb + (size_t)grow * FDIM + k0 + gchunk * 8;
            __builtin_amdgcn_global_load_lds(
                (const __attribute__((address_space(1))) void*)gp,
                (__attribute__((address_space(3))) void*)(lA + trow * BK), 16, 0, 0);
        }
#pragma unroll
        for (int i = 0; i < 4; ++i) {
            const int trow = wave * 32 + i * 8;
            const int grow = colBase + trow + srow;
            const unsigned short* gp = wt + (size_t)grow * FDIM + k0 + gchunk * 8;
            __builtin_amdgcn_global_load_lds(
                (const __attribute__((address_space(1))) void*)gp,
                (__attribute__((address_space(3))) void*)(lB + trow * BK), 16, 0, 0);
        }
        __syncthreads();

#pragma unroll
        for (int ks = 0; ks < 2; ++ks) {
            bf16x8 af[2], bfr[4];
            const int g = ks * 4 + kq;
#pragma unroll
            for (int mt = 0; mt < 2; ++mt) {
                const int row = wm + mt * 16 + fm;
                af[mt] = *(const bf16x8*)&lA[row * BK + ((g ^ (row & 7)) << 3)];
            }
#pragma unroll
            for (int nt = 0; nt < 4; ++nt) {
                const int row = wn + nt * 16 + fm;
                bfr[nt] = *(const bf16x8*)&lB[row * BK + ((g ^ (row & 7)) << 3)];
            }
#pragma unroll
            for (int mt = 0; mt < 2; ++mt)
#pragma unroll
                for (int nt = 0; nt < 4; ++nt)
                    acc[mt][nt] = __builtin_amdgcn_mfma_f32_16x16x32_bf16(
                        af[mt], bfr[nt], acc[mt][nt], 0, 0, 0);
        }
        __syncthreads();
    }

    const int rquad = lane >> 4;
#pragma unroll
    for (int nt = 0; nt < 4; ++nt) {
        const int col = colBase + wn + nt * 16 + fm;
        const float bias = (col < FDIM) ? bre[col] : bim[col - FDIM];
#pragma unroll
        for (int mt = 0; mt < 2; ++mt) {
            const int row0 = rowBase + wm + mt * 16 + rquad * 4;
#pragma unroll
            for (int r = 0; r < 4; ++r) {
                const int row = row0 + r;
                if (row < N_NODES)
                    y[(size_t)row * 1024 + col] = f2bf(acc[mt][nt][r] + bias);
            }
        }
    }
}

// ---------------------------------------------------------------------------
// K2: gather + complex combine + ReLU + fused BN stats.
// Block = 16 nodes (4 waves x 4 nodes). Coeffs preloaded (wave-uniform).
// LDS reduce layout lsum[g*512 + j*64 + lane] -> bank = lane%32 (conflict-free).
// 8-way replicated sums cut atomic chains to ~156.
// ---------------------------------------------------------------------------
__global__ __launch_bounds__(256) void evolve_stats(
    const unsigned short* __restrict__ y,
    const int* __restrict__ sub_nodes,
    const float* __restrict__ coef,
    unsigned short* __restrict__ eb,
    float* __restrict__ sums)
{
    __shared__ float lsum[2048];
    const int wave = threadIdx.x >> 6;
    const int lane = threadIdx.x & 63;
    const int f = lane << 3;

    float sR[8] = {0.f}, sR2[8] = {0.f}, sI[8] = {0.f}, sI2[8] = {0.f};

    for (int q = 0; q < 4; ++q) {
        const int n = blockIdx.x * 16 + wave * 4 + q;
        const float* cp = coef + (size_t)n * 12;
        const int* np = sub_nodes + n * SSZ;

        float aR[8] = {0.f}, aI[8] = {0.f};
#pragma unroll
        for (int s = 0; s < SSZ; ++s) {
            const float cr = cp[s], ci = cp[6 + s];
            const int nd = np[s];
            const unsigned short* base = y + (size_t)nd * 1024 + f;
            const u16x8 yr8 = *(const u16x8*)base;
            const u16x8 yi8 = *(const u16x8*)(base + FDIM);
#pragma unroll
            for (int j = 0; j < 8; ++j) {
                const float yr = bf2f(yr8[j]);
                const float yi = bf2f(yi8[j]);
                aR[j] = fmaf(cr, yr, fmaf(-ci, yi, aR[j]));
                aI[j] = fmaf(cr, yi, fmaf(ci, yr, aI[j]));
            }
        }
        u16x8 er8, ei8;
#pragma unroll
        for (int j = 0; j < 8; ++j) {
            const unsigned short re = f2bf(fmaxf(aR[j], 0.f));
            const unsigned short im = f2bf(fmaxf(aI[j], 0.f));
            er8[j] = re; ei8[j] = im;
            const float erv = bf2f(re), eiv = bf2f(im);
            sR[j] += erv;  sR2[j] = fmaf(erv, erv, sR2[j]);
            sI[j] += eiv;  sI2[j] = fmaf(eiv, eiv, sI2[j]);
        }
        *(u16x8*)(eb + (size_t)n * 1024 + f) = er8;
        *(u16x8*)(eb + (size_t)n * 1024 + FDIM + f) = ei8;
    }

    // cross-wave reduce, conflict-free layout: slot = g*512 + j*64 + lane
    if (wave == 0) {
#pragma unroll
        for (int j = 0; j < 8; ++j) {
            lsum[j * 64 + lane] = sR[j];
            lsum[512 + j * 64 + lane] = sR2[j];
            lsum[1024 + j * 64 + lane] = sI[j];
            lsum[1536 + j * 64 + lane] = sI2[j];
        }
    }
    for (int w = 1; w < 4; ++w) {
        __syncthreads();
        if (wave == w) {
#pragma unroll
            for (int j = 0; j < 8; ++j) {
                lsum[j * 64 + lane] += sR[j];
                lsum[512 + j * 64 + lane] += sR2[j];
                lsum[1024 + j * 64 + lane] += sI[j];
                lsum[1536 + j * 64 + lane] += sI2[j];
            }
        }
    }
    __syncthreads();

    float* sdst = sums + (blockIdx.x & (NCOPY - 1)) * 2048;
#pragma unroll
    for (int i = 0; i < 8; ++i) {
        const int idx = i * 256 + threadIdx.x;
        const int g = idx >> 9;
        const int s = idx & 511;
        const int feat = ((s & 63) << 3) + (s >> 6);
        atomicAdd(&sdst[g * 512 + feat], lsum[idx]);
    }
}

// ---------------------------------------------------------------------------
// K3: fold 8 sums copies + BN math into per-feature scale/shift
// ---------------------------------------------------------------------------
__global__ __launch_bounds__(512) void bnparams_kernel(
    const float* __restrict__ sums,
    const float* __restrict__ gr, const float* __restrict__ br_,
    const float* __restrict__ gi, const float* __restrict__ bi_,
    float* __restrict__ prm)
{
    const int f = threadIdx.x;
    float s1 = 0.f, s2 = 0.f, s3 = 0.f, s4 = 0.f;
#pragma unroll
    for (int c = 0; c < NCOPY; ++c) {
        const float* sc = sums + c * 2048;
        s1 += sc[f]; s2 += sc[512 + f]; s3 += sc[1024 + f]; s4 += sc[1536 + f];
    }
    const float invN = 1.0f / (float)N_NODES;
    const float mur = s1 * invN;
    const float varr = fmaf(-mur, mur, s2 * invN);
    const float scr = rsqrtf(varr + 1e-5f) * gr[f];
    prm[f] = scr;
    prm[512 + f] = fmaf(-mur, scr, br_[f]);
    const float mui = s3 * invN;
    const float vari = fmaf(-mui, mui, s4 * invN);
    const float sci = rsqrtf(vari + 1e-5f) * gi[f];
    prm[1024 + f] = sci;
    prm[1536 + f] = fmaf(-mui, sci, bi_[f]);
}

// ---------------------------------------------------------------------------
// K4: BN apply + residual; reads bf16 eb + fp32 x + prm, writes fp32 out
// ---------------------------------------------------------------------------
__global__ __launch_bounds__(256) void finalize_kernel(
    const float* __restrict__ x, const unsigned short* __restrict__ eb,
    const float* __restrict__ prm, float* __restrict__ out)
{
    const int gid = blockIdx.x * 256 + threadIdx.x;
    const int n = gid >> 6;
    const int f = (gid & 63) << 3;
    const u16x8 er8 = *(const u16x8*)(eb + (size_t)n * 1024 + f);
    const u16x8 ei8 = *(const u16x8*)(eb + (size_t)n * 1024 + FDIM + f);
    float orr[8], oii[8];
#pragma unroll
    for (int j = 0; j < 8; ++j) {
        const float scr = prm[f + j],        shr = prm[512 + f + j];
        const float sci = prm[1024 + f + j], shi = prm[1536 + f + j];
        const float xv = x[(size_t)n * FDIM + f + j];
        orr[j] = fmaf(bf2f(er8[j]), scr, shr) + xv;
        oii[j] = fmaf(bf2f(ei8[j]), sci, shi);
    }
#pragma unroll
    for (int j = 0; j < 8; j += 4) {
        *(float4*)(out + (size_t)n * 1024 + f + j) =
            make_float4(orr[j], orr[j + 1], orr[j + 2], orr[j + 3]);
        *(float4*)(out + (size_t)n * 1024 + FDIM + f + j) =
            make_float4(oii[j], oii[j + 1], oii[j + 2], oii[j + 3]);
    }
}

extern "C" void kernel_launch(void* const* d_in, const int* in_sizes, int n_in,
                              void* d_out, int out_size, void* d_ws, size_t ws_size,
                              hipStream_t stream)
{
    const float* x        = (const float*)d_in[0];
    const int* sub_nodes  = (const int*)d_in[2];
    const int* sub_adj    = (const int*)d_in[3];
    const float* Wre      = (const float*)d_in[4];
    const float* Wim      = (const float*)d_in[5];
    const float* bre      = (const float*)d_in[6];
    const float* bim      = (const float*)d_in[7];
    const float* gr       = (const float*)d_in[8];
    const float* br_      = (const float*)d_in[9];
    const float* gi       = (const float*)d_in[10];
    const float* bi_      = (const float*)d_in[11];
    float* out = (float*)d_out;

    // workspace layout; eb aliases xb+wt (dead after gemm)
    unsigned short* y  = (unsigned short*)d_ws;            // N*1024 bf16
    unsigned short* eb = y + (size_t)N_NODES * 1024;       // N*1024 bf16
    unsigned short* xb = eb;                               // N*512 bf16 (alias)
    unsigned short* wt = xb + (size_t)N_NODES * FDIM;      // 1024*512 bf16 (alias)
    float* coef = (float*)(eb + (size_t)N_NODES * 1024);   // N*12
    float* sums = coef + (size_t)N_NODES * 12;             // 8*2048
    float* prm  = sums + NCOPY * 2048;                     // 2048

    conv_all<<<5599, 256, 0, stream>>>(x, Wre, Wim, sub_adj, xb, wt, coef, sums);

    dim3 gg(1024 / BN, (N_NODES + BM - 1) / BM);
    gemm_mfma<<<gg, 256, 0, stream>>>(xb, wt, bre, bim, y);

    evolve_stats<<<N_NODES / 16, 256, 0, stream>>>(y, sub_nodes, coef, eb, sums);

    bnparams_kernel<<<1, 512, 0, stream>>>(sums, gr, br_, gi, bi_, prm);

    finalize_kernel<<<(N_NODES * 64) / 256, 256, 0, stream>>>(x, eb, prm, out);
}

// Round 6
// 256.225 us; speedup vs baseline: 1.3074x; 1.3074x over previous
//
#include <hip/hip_runtime.h>

#define N_NODES 20000
#define FDIM 512
#define SSZ 6
#define NCOPY 8

typedef __attribute__((ext_vector_type(8))) short bf16x8;
typedef __attribute__((ext_vector_type(4))) float f32x4;
typedef __attribute__((ext_vector_type(8))) unsigned short u16x8;

static __device__ __forceinline__ unsigned short f2bf(float f) {
    unsigned int u = __float_as_uint(f);
    unsigned int r = (u + 0x7fffu + ((u >> 16) & 1u)) >> 16;
    return (unsigned short)r;
}
static __device__ __forceinline__ float bf2f(unsigned short u) {
    return __uint_as_float(((unsigned int)u) << 16);
}

// ---------------------------------------------------------------------------
// K0: fused prep.
//  blocks [0,5000)      : x -> bf16
//  blocks [5000,5512)   : W^T bf16
//  blocks [5512,5591)   : per-node unitary coefficients (12 floats/node)
//  blocks [5591,5599)   : zero sums[8*2048]
// ---------------------------------------------------------------------------
__global__ __launch_bounds__(256) void conv_all(
    const float* __restrict__ x, const float* __restrict__ Wre,
    const float* __restrict__ Wim, const int* __restrict__ sub_adj,
    unsigned short* __restrict__ xb, unsigned short* __restrict__ wt,
    float* __restrict__ coef, float* __restrict__ sums)
{
    const int blk = blockIdx.x;
    const int tid = threadIdx.x;
    if (blk < 5000) {
        const size_t i = ((size_t)blk * 256 + tid) * 8;
        const float4 a = *(const float4*)(x + i);
        const float4 b = *(const float4*)(x + i + 4);
        u16x8 o;
        o[0] = f2bf(a.x); o[1] = f2bf(a.y); o[2] = f2bf(a.z); o[3] = f2bf(a.w);
        o[4] = f2bf(b.x); o[5] = f2bf(b.y); o[6] = f2bf(b.z); o[7] = f2bf(b.w);
        *(u16x8*)(xb + i) = o;
    } else if (blk < 5512) {
        __shared__ float tile[32][33];
        const int bidx = blk - 5000;
        const int z = bidx >> 8;
        const int rem = bidx & 255;
        const int k0 = (rem & 15) * 32;
        const int n0 = (rem >> 4) * 32;
        const float* W = z ? Wim : Wre;
        const int tx = tid & 31, ty = tid >> 5;
#pragma unroll
        for (int i = 0; i < 4; ++i)
            tile[ty + i * 8][tx] = W[(size_t)(k0 + ty + i * 8) * FDIM + n0 + tx];
        __syncthreads();
        unsigned short* wtb = wt + (size_t)z * FDIM * FDIM;
#pragma unroll
        for (int i = 0; i < 4; ++i)
            wtb[(size_t)(n0 + ty + i * 8) * FDIM + k0 + tx] = f2bf(tile[tx][ty + i * 8]);
    } else if (blk < 5591) {
        const int c = (blk - 5512) * 256 + tid;
        if (c < N_NODES) {
            const int* sa = sub_adj + (size_t)c * (SSZ * SSZ);
            float A[SSZ][SSZ], deg[SSZ];
#pragma unroll
            for (int s = 0; s < SSZ; ++s) {
                float d = 0.f;
#pragma unroll
                for (int t = 0; t < SSZ; ++t) { float a = (float)sa[s * SSZ + t]; A[s][t] = a; d += a; }
                deg[s] = d;
            }
            float p1[SSZ], p2[SSZ], p3[SSZ], p4[SSZ];
#pragma unroll
            for (int t = 0; t < SSZ; ++t) p1[t] = ((t == 0) ? deg[0] : 0.f) - A[0][t];
#pragma unroll
            for (int t = 0; t < SSZ; ++t) {
                float acc = 0.f;
#pragma unroll
                for (int s = 0; s < SSZ; ++s) acc += p1[s] * (((s == t) ? deg[s] : 0.f) - A[s][t]);
                p2[t] = acc;
            }
#pragma unroll
            for (int t = 0; t < SSZ; ++t) {
                float acc = 0.f;
#pragma unroll
                for (int s = 0; s < SSZ; ++s) acc += p2[s] * (((s == t) ? deg[s] : 0.f) - A[s][t]);
                p3[t] = acc;
            }
#pragma unroll
            for (int t = 0; t < SSZ; ++t) {
                float acc = 0.f;
#pragma unroll
                for (int s = 0; s < SSZ; ++s) acc += p3[s] * (((s == t) ? deg[s] : 0.f) - A[s][t]);
                p4[t] = acc;
            }
#pragma unroll
            for (int t = 0; t < SSZ; ++t) {
                coef[(size_t)c * 12 + t] =
                    ((t == 0) ? 1.f : 0.f) - 3.125e-4f * p2[t] + 1.6276041666666668e-8f * p4[t];
                coef[(size_t)c * 12 + 6 + t] =
                    -0.025f * p1[t] + 2.6041666666666666e-6f * p3[t];
            }
        }
    } else {
        const int base = (blk - 5591) * 2048;
#pragma unroll
        for (int i = 0; i < 8; ++i) sums[base + i * 256 + tid] = 0.f;
    }
}

// ---------------------------------------------------------------------------
// K1: bf16 MFMA GEMM.  y[20000][1024] = xb @ wt^T + bias (bf16 out)
// 64x128 tile, BK=64, 4 waves (2x2, wave tile 32x64), 2x4 frags 16x16x32.
// ---------------------------------------------------------------------------
#define BM 64
#define BN 128
#define BK 64

__global__ __launch_bounds__(256) void gemm_mfma(
    const unsigned short* __restrict__ xb,
    const unsigned short* __restrict__ wt,
    const float* __restrict__ bre, const float* __restrict__ bim,
    unsigned short* __restrict__ y)
{
    __shared__ __align__(16) unsigned short lA[BM * BK];
    __shared__ __align__(16) unsigned short lB[BN * BK];

    const int tid  = threadIdx.x;
    const int wave = tid >> 6;
    const int lane = tid & 63;
    const int rowBase = blockIdx.y * BM;
    const int colBase = blockIdx.x * BN;

    const int wm = (wave >> 1) * 32;
    const int wn = (wave & 1) * 64;

    f32x4 acc[2][4];
#pragma unroll
    for (int i = 0; i < 2; ++i)
#pragma unroll
        for (int j = 0; j < 4; ++j) acc[i][j] = (f32x4){0.f, 0.f, 0.f, 0.f};

    const int srow   = lane >> 3;
    const int schunk = lane & 7;
    const int gchunk = schunk ^ srow;

    const int fm = lane & 15;
    const int kq = lane >> 4;

    for (int k0 = 0; k0 < FDIM; k0 += BK) {
#pragma unroll
        for (int i = 0; i < 2; ++i) {
            const int trow = wave * 16 + i * 8;
            int grow = rowBase + trow + srow;
            if (grow > N_NODES - 1) grow = N_NODES - 1;
            const unsigned short* gp = xb + (size_t)grow * FDIM + k0 + gchunk * 8;
            __builtin_amdgcn_global_load_lds(
                (const __attribute__((address_space(1))) void*)gp,
                (__attribute__((address_space(3))) void*)(lA + trow * BK), 16, 0, 0);
        }
#pragma unroll
        for (int i = 0; i < 4; ++i) {
            const int trow = wave * 32 + i * 8;
            const int grow = colBase + trow + srow;
            const unsigned short* gp = wt + (size_t)grow * FDIM + k0 + gchunk * 8;
            __builtin_amdgcn_global_load_lds(
                (const __attribute__((address_space(1))) void*)gp,
                (__attribute__((address_space(3))) void*)(lB + trow * BK), 16, 0, 0);
        }
        __syncthreads();

#pragma unroll
        for (int ks = 0; ks < 2; ++ks) {
            bf16x8 af[2], bfr[4];
            const int g = ks * 4 + kq;
#pragma unroll
            for (int mt = 0; mt < 2; ++mt) {
                const int row = wm + mt * 16 + fm;
                af[mt] = *(const bf16x8*)&lA[row * BK + ((g ^ (row & 7)) << 3)];
            }
#pragma unroll
            for (int nt = 0; nt < 4; ++nt) {
                const int row = wn + nt * 16 + fm;
                bfr[nt] = *(const bf16x8*)&lB[row * BK + ((g ^ (row & 7)) << 3)];
            }
#pragma unroll
            for (int mt = 0; mt < 2; ++mt)
#pragma unroll
                for (int nt = 0; nt < 4; ++nt)
                    acc[mt][nt] = __builtin_amdgcn_mfma_f32_16x16x32_bf16(
                        af[mt], bfr[nt], acc[mt][nt], 0, 0, 0);
        }
        __syncthreads();
    }

    const int rquad = lane >> 4;
#pragma unroll
    for (int nt = 0; nt < 4; ++nt) {
        const int col = colBase + wn + nt * 16 + fm;
        const float bias = (col < FDIM) ? bre[col] : bim[col - FDIM];
#pragma unroll
        for (int mt = 0; mt < 2; ++mt) {
            const int row0 = rowBase + wm + mt * 16 + rquad * 4;
#pragma unroll
            for (int r = 0; r < 4; ++r) {
                const int row = row0 + r;
                if (row < N_NODES)
                    y[(size_t)row * 1024 + col] = f2bf(acc[mt][nt][r] + bias);
            }
        }
    }
}

// ---------------------------------------------------------------------------
// K2: gather + complex combine + ReLU + fused BN stats.
// Block = 16 nodes (4 waves x 4 nodes). Coeffs precomputed (wave-uniform).
// LDS reduce layout lsum[g*512 + j*64 + lane] (conflict-free accumulate).
// Atomics in SLOT order (coalesced, 64 consecutive dwords per wave) into
// 8-way replicated sums; bnparams unpermutes. (R5's permuted scatter caused
// L2 line thrash: WRITE_SIZE 50->120 MB, 56->130 us. Keep atomics coalesced.)
// ---------------------------------------------------------------------------
__global__ __launch_bounds__(256) void evolve_stats(
    const unsigned short* __restrict__ y,
    const int* __restrict__ sub_nodes,
    const float* __restrict__ coef,
    unsigned short* __restrict__ eb,
    float* __restrict__ sums)
{
    __shared__ float lsum[2048];
    const int wave = threadIdx.x >> 6;
    const int lane = threadIdx.x & 63;
    const int f = lane << 3;

    float sR[8] = {0.f}, sR2[8] = {0.f}, sI[8] = {0.f}, sI2[8] = {0.f};

    for (int q = 0; q < 4; ++q) {
        const int n = blockIdx.x * 16 + wave * 4 + q;
        const float* cp = coef + (size_t)n * 12;
        const int* np = sub_nodes + n * SSZ;

        float aR[8] = {0.f}, aI[8] = {0.f};
#pragma unroll
        for (int s = 0; s < SSZ; ++s) {
            const float cr = cp[s], ci = cp[6 + s];
            const int nd = np[s];
            const unsigned short* base = y + (size_t)nd * 1024 + f;
            const u16x8 yr8 = *(const u16x8*)base;
            const u16x8 yi8 = *(const u16x8*)(base + FDIM);
#pragma unroll
            for (int j = 0; j < 8; ++j) {
                const float yr = bf2f(yr8[j]);
                const float yi = bf2f(yi8[j]);
                aR[j] = fmaf(cr, yr, fmaf(-ci, yi, aR[j]));
                aI[j] = fmaf(cr, yi, fmaf(ci, yr, aI[j]));
            }
        }
        u16x8 er8, ei8;
#pragma unroll
        for (int j = 0; j < 8; ++j) {
            const unsigned short re = f2bf(fmaxf(aR[j], 0.f));
            const unsigned short im = f2bf(fmaxf(aI[j], 0.f));
            er8[j] = re; ei8[j] = im;
            const float erv = bf2f(re), eiv = bf2f(im);
            sR[j] += erv;  sR2[j] = fmaf(erv, erv, sR2[j]);
            sI[j] += eiv;  sI2[j] = fmaf(eiv, eiv, sI2[j]);
        }
        *(u16x8*)(eb + (size_t)n * 1024 + f) = er8;
        *(u16x8*)(eb + (size_t)n * 1024 + FDIM + f) = ei8;
    }

    // cross-wave reduce, conflict-free layout: slot = g*512 + j*64 + lane
    if (wave == 0) {
#pragma unroll
        for (int j = 0; j < 8; ++j) {
            lsum[j * 64 + lane] = sR[j];
            lsum[512 + j * 64 + lane] = sR2[j];
            lsum[1024 + j * 64 + lane] = sI[j];
            lsum[1536 + j * 64 + lane] = sI2[j];
        }
    }
    for (int w = 1; w < 4; ++w) {
        __syncthreads();
        if (wave == w) {
#pragma unroll
            for (int j = 0; j < 8; ++j) {
                lsum[j * 64 + lane] += sR[j];
                lsum[512 + j * 64 + lane] += sR2[j];
                lsum[1024 + j * 64 + lane] += sI[j];
                lsum[1536 + j * 64 + lane] += sI2[j];
            }
        }
    }
    __syncthreads();

    // coalesced atomics in slot order; sums kept in slot layout
    float* sdst = sums + (blockIdx.x & (NCOPY - 1)) * 2048;
#pragma unroll
    for (int i = 0; i < 8; ++i) {
        const int idx = i * 256 + threadIdx.x;
        atomicAdd(&sdst[idx], lsum[idx]);
    }
}

// ---------------------------------------------------------------------------
// K3: fold 8 sums copies (slot layout: slot = ((f&7)<<6)|(f>>3)) + BN math
// into per-feature scale/shift
// ---------------------------------------------------------------------------
__global__ __launch_bounds__(512) void bnparams_kernel(
    const float* __restrict__ sums,
    const float* __restrict__ gr, const float* __restrict__ br_,
    const float* __restrict__ gi, const float* __restrict__ bi_,
    float* __restrict__ prm)
{
    const int f = threadIdx.x;
    const int slot = ((f & 7) << 6) | (f >> 3);
    float s1 = 0.f, s2 = 0.f, s3 = 0.f, s4 = 0.f;
#pragma unroll
    for (int c = 0; c < NCOPY; ++c) {
        const float* sc = sums + c * 2048;
        s1 += sc[slot]; s2 += sc[512 + slot]; s3 += sc[1024 + slot]; s4 += sc[1536 + slot];
    }
    const float invN = 1.0f / (float)N_NODES;
    const float mur = s1 * invN;
    const float varr = fmaf(-mur, mur, s2 * invN);
    const float scr = rsqrtf(varr + 1e-5f) * gr[f];
    prm[f] = scr;
    prm[512 + f] = fmaf(-mur, scr, br_[f]);
    const float mui = s3 * invN;
    const float vari = fmaf(-mui, mui, s4 * invN);
    const float sci = rsqrtf(vari + 1e-5f) * gi[f];
    prm[1024 + f] = sci;
    prm[1536 + f] = fmaf(-mui, sci, bi_[f]);
}

// ---------------------------------------------------------------------------
// K4: BN apply + residual; reads bf16 eb + fp32 x + prm, writes fp32 out
// ---------------------------------------------------------------------------
__global__ __launch_bounds__(256) void finalize_kernel(
    const float* __restrict__ x, const unsigned short* __restrict__ eb,
    const float* __restrict__ prm, float* __restrict__ out)
{
    const int gid = blockIdx.x * 256 + threadIdx.x;
    const int n = gid >> 6;
    const int f = (gid & 63) << 3;
    const u16x8 er8 = *(const u16x8*)(eb + (size_t)n * 1024 + f);
    const u16x8 ei8 = *(const u16x8*)(eb + (size_t)n * 1024 + FDIM + f);
    float orr[8], oii[8];
#pragma unroll
    for (int j = 0; j < 8; ++j) {
        const float scr = prm[f + j],        shr = prm[512 + f + j];
        const float sci = prm[1024 + f + j], shi = prm[1536 + f + j];
        const float xv = x[(size_t)n * FDIM + f + j];
        orr[j] = fmaf(bf2f(er8[j]), scr, shr) + xv;
        oii[j] = fmaf(bf2f(ei8[j]), sci, shi);
    }
#pragma unroll
    for (int j = 0; j < 8; j += 4) {
        *(float4*)(out + (size_t)n * 1024 + f + j) =
            make_float4(orr[j], orr[j + 1], orr[j + 2], orr[j + 3]);
        *(float4*)(out + (size_t)n * 1024 + FDIM + f + j) =
            make_float4(oii[j], oii[j + 1], oii[j + 2], oii[j + 3]);
    }
}

extern "C" void kernel_launch(void* const* d_in, const int* in_sizes, int n_in,
                              void* d_out, int out_size, void* d_ws, size_t ws_size,
                              hipStream_t stream)
{
    const float* x        = (const float*)d_in[0];
    const int* sub_nodes  = (const int*)d_in[2];
    const int* sub_adj    = (const int*)d_in[3];
    const float* Wre      = (const float*)d_in[4];
    const float* Wim      = (const float*)d_in[5];
    const float* bre      = (const float*)d_in[6];
    const float* bim      = (const float*)d_in[7];
    const float* gr       = (const float*)d_in[8];
    const float* br_      = (const float*)d_in[9];
    const float* gi       = (const float*)d_in[10];
    const float* bi_      = (const float*)d_in[11];
    float* out = (float*)d_out;

    // workspace layout; eb aliases xb+wt (dead after gemm)
    unsigned short* y  = (unsigned short*)d_ws;            // N*1024 bf16
    unsigned short* eb = y + (size_t)N_NODES * 1024;       // N*1024 bf16
    unsigned short* xb = eb;                               // N*512 bf16 (alias)
    unsigned short* wt = xb + (size_t)N_NODES * FDIM;      // 1024*512 bf16 (alias)
    float* coef = (float*)(eb + (size_t)N_NODES * 1024);   // N*12
    float* sums = coef + (size_t)N_NODES * 12;             // 8*2048
    float* prm  = sums + NCOPY * 2048;                     // 2048

    conv_all<<<5599, 256, 0, stream>>>(x, Wre, Wim, sub_adj, xb, wt, coef, sums);

    dim3 gg(1024 / BN, (N_NODES + BM - 1) / BM);
    gemm_mfma<<<gg, 256, 0, stream>>>(xb, wt, bre, bim, y);

    evolve_stats<<<N_NODES / 16, 256, 0, stream>>>(y, sub_nodes, coef, eb, sums);

    bnparams_kernel<<<1, 512, 0, stream>>>(sums, gr, br_, gi, bi_, prm);

    finalize_kernel<<<(N_NODES * 64) / 256, 256, 0, stream>>>(x, eb, prm, out);
}

// Round 7
// 256.033 us; speedup vs baseline: 1.3084x; 1.0008x over previous
//
#include <hip/hip_runtime.h>

#define N_NODES 20000
#define FDIM 512
#define SSZ 6
#define NCOPY 8

typedef __attribute__((ext_vector_type(8))) short bf16x8;
typedef __attribute__((ext_vector_type(4))) float f32x4;
typedef __attribute__((ext_vector_type(8))) unsigned short u16x8;

static __device__ __forceinline__ unsigned short f2bf(float f) {
    unsigned int u = __float_as_uint(f);
    unsigned int r = (u + 0x7fffu + ((u >> 16) & 1u)) >> 16;
    return (unsigned short)r;
}
static __device__ __forceinline__ float bf2f(unsigned short u) {
    return __uint_as_float(((unsigned int)u) << 16);
}

// ---------------------------------------------------------------------------
// K0: fused prep.
//  blocks [0,5000)      : x -> bf16
//  blocks [5000,5512)   : W^T bf16
//  blocks [5512,5591)   : per-node unitary coefficients (12 floats/node)
//  blocks [5591,5599)   : zero sums[8*2048]
// ---------------------------------------------------------------------------
__global__ __launch_bounds__(256) void conv_all(
    const float* __restrict__ x, const float* __restrict__ Wre,
    const float* __restrict__ Wim, const int* __restrict__ sub_adj,
    unsigned short* __restrict__ xb, unsigned short* __restrict__ wt,
    float* __restrict__ coef, float* __restrict__ sums)
{
    const int blk = blockIdx.x;
    const int tid = threadIdx.x;
    if (blk < 5000) {
        const size_t i = ((size_t)blk * 256 + tid) * 8;
        const float4 a = *(const float4*)(x + i);
        const float4 b = *(const float4*)(x + i + 4);
        u16x8 o;
        o[0] = f2bf(a.x); o[1] = f2bf(a.y); o[2] = f2bf(a.z); o[3] = f2bf(a.w);
        o[4] = f2bf(b.x); o[5] = f2bf(b.y); o[6] = f2bf(b.z); o[7] = f2bf(b.w);
        *(u16x8*)(xb + i) = o;
    } else if (blk < 5512) {
        __shared__ float tile[32][33];
        const int bidx = blk - 5000;
        const int z = bidx >> 8;
        const int rem = bidx & 255;
        const int k0 = (rem & 15) * 32;
        const int n0 = (rem >> 4) * 32;
        const float* W = z ? Wim : Wre;
        const int tx = tid & 31, ty = tid >> 5;
#pragma unroll
        for (int i = 0; i < 4; ++i)
            tile[ty + i * 8][tx] = W[(size_t)(k0 + ty + i * 8) * FDIM + n0 + tx];
        __syncthreads();
        unsigned short* wtb = wt + (size_t)z * FDIM * FDIM;
#pragma unroll
        for (int i = 0; i < 4; ++i)
            wtb[(size_t)(n0 + ty + i * 8) * FDIM + k0 + tx] = f2bf(tile[tx][ty + i * 8]);
    } else if (blk < 5591) {
        const int c = (blk - 5512) * 256 + tid;
        if (c < N_NODES) {
            const int* sa = sub_adj + (size_t)c * (SSZ * SSZ);
            float A[SSZ][SSZ], deg[SSZ];
#pragma unroll
            for (int s = 0; s < SSZ; ++s) {
                float d = 0.f;
#pragma unroll
                for (int t = 0; t < SSZ; ++t) { float a = (float)sa[s * SSZ + t]; A[s][t] = a; d += a; }
                deg[s] = d;
            }
            float p1[SSZ], p2[SSZ], p3[SSZ], p4[SSZ];
#pragma unroll
            for (int t = 0; t < SSZ; ++t) p1[t] = ((t == 0) ? deg[0] : 0.f) - A[0][t];
#pragma unroll
            for (int t = 0; t < SSZ; ++t) {
                float acc = 0.f;
#pragma unroll
                for (int s = 0; s < SSZ; ++s) acc += p1[s] * (((s == t) ? deg[s] : 0.f) - A[s][t]);
                p2[t] = acc;
            }
#pragma unroll
            for (int t = 0; t < SSZ; ++t) {
                float acc = 0.f;
#pragma unroll
                for (int s = 0; s < SSZ; ++s) acc += p2[s] * (((s == t) ? deg[s] : 0.f) - A[s][t]);
                p3[t] = acc;
            }
#pragma unroll
            for (int t = 0; t < SSZ; ++t) {
                float acc = 0.f;
#pragma unroll
                for (int s = 0; s < SSZ; ++s) acc += p3[s] * (((s == t) ? deg[s] : 0.f) - A[s][t]);
                p4[t] = acc;
            }
#pragma unroll
            for (int t = 0; t < SSZ; ++t) {
                coef[(size_t)c * 12 + t] =
                    ((t == 0) ? 1.f : 0.f) - 3.125e-4f * p2[t] + 1.6276041666666668e-8f * p4[t];
                coef[(size_t)c * 12 + 6 + t] =
                    -0.025f * p1[t] + 2.6041666666666666e-6f * p3[t];
            }
        }
    } else {
        const int base = (blk - 5591) * 2048;
#pragma unroll
        for (int i = 0; i < 8; ++i) sums[base + i * 256 + tid] = 0.f;
    }
}

// ---------------------------------------------------------------------------
// K1: bf16 MFMA GEMM.  y[20000][1024] = xb @ wt^T + bias (bf16 out)
// 64x128 tile, BK=64, 4 waves (2x2, wave tile 32x64), 2x4 frags 16x16x32.
// XCD swizzle: b = rq + 8*c + 64*rg so (round-robin xcd = b&7) depends only
// on the row-block -> all 8 col-tiles of a row share one XCD's L2, xb fetched
// ~once instead of ~4x. Invalid rows (313..319) exit immediately.
// ---------------------------------------------------------------------------
#define BM 64
#define BN 128
#define BK 64

__global__ __launch_bounds__(256) void gemm_mfma(
    const unsigned short* __restrict__ xb,
    const unsigned short* __restrict__ wt,
    const float* __restrict__ bre, const float* __restrict__ bim,
    unsigned short* __restrict__ y)
{
    const int b = blockIdx.x;
    const int rowTile = (b >> 6) * 8 + (b & 7);
    if (rowTile >= 313) return;
    const int rowBase = rowTile * BM;
    const int colBase = ((b >> 3) & 7) * BN;

    __shared__ __align__(16) unsigned short lA[BM * BK];
    __shared__ __align__(16) unsigned short lB[BN * BK];

    const int tid  = threadIdx.x;
    const int wave = tid >> 6;
    const int lane = tid & 63;

    const int wm = (wave >> 1) * 32;
    const int wn = (wave & 1) * 64;

    f32x4 acc[2][4];
#pragma unroll
    for (int i = 0; i < 2; ++i)
#pragma unroll
        for (int j = 0; j < 4; ++j) acc[i][j] = (f32x4){0.f, 0.f, 0.f, 0.f};

    const int srow   = lane >> 3;
    const int schunk = lane & 7;
    const int gchunk = schunk ^ srow;

    const int fm = lane & 15;
    const int kq = lane >> 4;

    for (int k0 = 0; k0 < FDIM; k0 += BK) {
#pragma unroll
        for (int i = 0; i < 2; ++i) {
            const int trow = wave * 16 + i * 8;
            int grow = rowBase + trow + srow;
            if (grow > N_NODES - 1) grow = N_NODES - 1;
            const unsigned short* gp = xb + (size_t)grow * FDIM + k0 + gchunk * 8;
            __builtin_amdgcn_global_load_lds(
                (const __attribute__((address_space(1))) void*)gp,
                (__attribute__((address_space(3))) void*)(lA + trow * BK), 16, 0, 0);
        }
#pragma unroll
        for (int i = 0; i < 4; ++i) {
            const int trow = wave * 32 + i * 8;
            const int grow = colBase + trow + srow;
            const unsigned short* gp = wt + (size_t)grow * FDIM + k0 + gchunk * 8;
            __builtin_amdgcn_global_load_lds(
                (const __attribute__((address_space(1))) void*)gp,
                (__attribute__((address_space(3))) void*)(lB + trow * BK), 16, 0, 0);
        }
        __syncthreads();

#pragma unroll
        for (int ks = 0; ks < 2; ++ks) {
            bf16x8 af[2], bfr[4];
            const int g = ks * 4 + kq;
#pragma unroll
            for (int mt = 0; mt < 2; ++mt) {
                const int row = wm + mt * 16 + fm;
                af[mt] = *(const bf16x8*)&lA[row * BK + ((g ^ (row & 7)) << 3)];
            }
#pragma unroll
            for (int nt = 0; nt < 4; ++nt) {
                const int row = wn + nt * 16 + fm;
                bfr[nt] = *(const bf16x8*)&lB[row * BK + ((g ^ (row & 7)) << 3)];
            }
#pragma unroll
            for (int mt = 0; mt < 2; ++mt)
#pragma unroll
                for (int nt = 0; nt < 4; ++nt)
                    acc[mt][nt] = __builtin_amdgcn_mfma_f32_16x16x32_bf16(
                        af[mt], bfr[nt], acc[mt][nt], 0, 0, 0);
        }
        __syncthreads();
    }

    const int rquad = lane >> 4;
#pragma unroll
    for (int nt = 0; nt < 4; ++nt) {
        const int col = colBase + wn + nt * 16 + fm;
        const float bias = (col < FDIM) ? bre[col] : bim[col - FDIM];
#pragma unroll
        for (int mt = 0; mt < 2; ++mt) {
            const int row0 = rowBase + wm + mt * 16 + rquad * 4;
#pragma unroll
            for (int r = 0; r < 4; ++r) {
                const int row = row0 + r;
                if (row < N_NODES)
                    y[(size_t)row * 1024 + col] = f2bf(acc[mt][nt][r] + bias);
            }
        }
    }
}

// ---------------------------------------------------------------------------
// K2: gather + complex combine + ReLU + fused BN stats.
// Block = 32 nodes (4 waves x 8 nodes) -> 625 blocks, halved atomic traffic.
// eb written nontemporal to keep y resident in L2 during the gather.
// Atomics in slot order (coalesced); bnparams unpermutes.
// ---------------------------------------------------------------------------
__global__ __launch_bounds__(256) void evolve_stats(
    const unsigned short* __restrict__ y,
    const int* __restrict__ sub_nodes,
    const float* __restrict__ coef,
    unsigned short* __restrict__ eb,
    float* __restrict__ sums)
{
    __shared__ float lsum[2048];
    const int wave = threadIdx.x >> 6;
    const int lane = threadIdx.x & 63;
    const int f = lane << 3;

    float sR[8] = {0.f}, sR2[8] = {0.f}, sI[8] = {0.f}, sI2[8] = {0.f};

    for (int q = 0; q < 8; ++q) {
        const int n = blockIdx.x * 32 + wave * 8 + q;
        const float* cp = coef + (size_t)n * 12;
        const int* np = sub_nodes + n * SSZ;

        float aR[8] = {0.f}, aI[8] = {0.f};
#pragma unroll
        for (int s = 0; s < SSZ; ++s) {
            const float cr = cp[s], ci = cp[6 + s];
            const int nd = np[s];
            const unsigned short* base = y + (size_t)nd * 1024 + f;
            const u16x8 yr8 = *(const u16x8*)base;
            const u16x8 yi8 = *(const u16x8*)(base + FDIM);
#pragma unroll
            for (int j = 0; j < 8; ++j) {
                const float yr = bf2f(yr8[j]);
                const float yi = bf2f(yi8[j]);
                aR[j] = fmaf(cr, yr, fmaf(-ci, yi, aR[j]));
                aI[j] = fmaf(cr, yi, fmaf(ci, yr, aI[j]));
            }
        }
        u16x8 er8, ei8;
#pragma unroll
        for (int j = 0; j < 8; ++j) {
            const unsigned short re = f2bf(fmaxf(aR[j], 0.f));
            const unsigned short im = f2bf(fmaxf(aI[j], 0.f));
            er8[j] = re; ei8[j] = im;
            const float erv = bf2f(re), eiv = bf2f(im);
            sR[j] += erv;  sR2[j] = fmaf(erv, erv, sR2[j]);
            sI[j] += eiv;  sI2[j] = fmaf(eiv, eiv, sI2[j]);
        }
        __builtin_nontemporal_store(er8, (u16x8*)(eb + (size_t)n * 1024 + f));
        __builtin_nontemporal_store(ei8, (u16x8*)(eb + (size_t)n * 1024 + FDIM + f));
    }

    // cross-wave reduce, conflict-free layout: slot = g*512 + j*64 + lane
    if (wave == 0) {
#pragma unroll
        for (int j = 0; j < 8; ++j) {
            lsum[j * 64 + lane] = sR[j];
            lsum[512 + j * 64 + lane] = sR2[j];
            lsum[1024 + j * 64 + lane] = sI[j];
            lsum[1536 + j * 64 + lane] = sI2[j];
        }
    }
    for (int w = 1; w < 4; ++w) {
        __syncthreads();
        if (wave == w) {
#pragma unroll
            for (int j = 0; j < 8; ++j) {
                lsum[j * 64 + lane] += sR[j];
                lsum[512 + j * 64 + lane] += sR2[j];
                lsum[1024 + j * 64 + lane] += sI[j];
                lsum[1536 + j * 64 + lane] += sI2[j];
            }
        }
    }
    __syncthreads();

    // coalesced atomics in slot order; sums kept in slot layout
    float* sdst = sums + (blockIdx.x & (NCOPY - 1)) * 2048;
#pragma unroll
    for (int i = 0; i < 8; ++i) {
        const int idx = i * 256 + threadIdx.x;
        atomicAdd(&sdst[idx], lsum[idx]);
    }
}

// ---------------------------------------------------------------------------
// K3: fold 8 sums copies (slot layout: slot = ((f&7)<<6)|(f>>3)) + BN math
// ---------------------------------------------------------------------------
__global__ __launch_bounds__(512) void bnparams_kernel(
    const float* __restrict__ sums,
    const float* __restrict__ gr, const float* __restrict__ br_,
    const float* __restrict__ gi, const float* __restrict__ bi_,
    float* __restrict__ prm)
{
    const int f = threadIdx.x;
    const int slot = ((f & 7) << 6) | (f >> 3);
    float s1 = 0.f, s2 = 0.f, s3 = 0.f, s4 = 0.f;
#pragma unroll
    for (int c = 0; c < NCOPY; ++c) {
        const float* sc = sums + c * 2048;
        s1 += sc[slot]; s2 += sc[512 + slot]; s3 += sc[1024 + slot]; s4 += sc[1536 + slot];
    }
    const float invN = 1.0f / (float)N_NODES;
    const float mur = s1 * invN;
    const float varr = fmaf(-mur, mur, s2 * invN);
    const float scr = rsqrtf(varr + 1e-5f) * gr[f];
    prm[f] = scr;
    prm[512 + f] = fmaf(-mur, scr, br_[f]);
    const float mui = s3 * invN;
    const float vari = fmaf(-mui, mui, s4 * invN);
    const float sci = rsqrtf(vari + 1e-5f) * gi[f];
    prm[1024 + f] = sci;
    prm[1536 + f] = fmaf(-mui, sci, bi_[f]);
}

// ---------------------------------------------------------------------------
// K4: BN apply + residual; nontemporal out stores (never re-read)
// ---------------------------------------------------------------------------
__global__ __launch_bounds__(256) void finalize_kernel(
    const float* __restrict__ x, const unsigned short* __restrict__ eb,
    const float* __restrict__ prm, float* __restrict__ out)
{
    const int gid = blockIdx.x * 256 + threadIdx.x;
    const int n = gid >> 6;
    const int f = (gid & 63) << 3;
    const u16x8 er8 = *(const u16x8*)(eb + (size_t)n * 1024 + f);
    const u16x8 ei8 = *(const u16x8*)(eb + (size_t)n * 1024 + FDIM + f);
    float orr[8], oii[8];
#pragma unroll
    for (int j = 0; j < 8; ++j) {
        const float scr = prm[f + j],        shr = prm[512 + f + j];
        const float sci = prm[1024 + f + j], shi = prm[1536 + f + j];
        const float xv = x[(size_t)n * FDIM + f + j];
        orr[j] = fmaf(bf2f(er8[j]), scr, shr) + xv;
        oii[j] = fmaf(bf2f(ei8[j]), sci, shi);
    }
#pragma unroll
    for (int j = 0; j < 8; j += 4) {
        const f32x4 vr = {orr[j], orr[j + 1], orr[j + 2], orr[j + 3]};
        const f32x4 vi = {oii[j], oii[j + 1], oii[j + 2], oii[j + 3]};
        __builtin_nontemporal_store(vr, (f32x4*)(out + (size_t)n * 1024 + f + j));
        __builtin_nontemporal_store(vi, (f32x4*)(out + (size_t)n * 1024 + FDIM + f + j));
    }
}

extern "C" void kernel_launch(void* const* d_in, const int* in_sizes, int n_in,
                              void* d_out, int out_size, void* d_ws, size_t ws_size,
                              hipStream_t stream)
{
    const float* x        = (const float*)d_in[0];
    const int* sub_nodes  = (const int*)d_in[2];
    const int* sub_adj    = (const int*)d_in[3];
    const float* Wre      = (const float*)d_in[4];
    const float* Wim      = (const float*)d_in[5];
    const float* bre      = (const float*)d_in[6];
    const float* bim      = (const float*)d_in[7];
    const float* gr       = (const float*)d_in[8];
    const float* br_      = (const float*)d_in[9];
    const float* gi       = (const float*)d_in[10];
    const float* bi_      = (const float*)d_in[11];
    float* out = (float*)d_out;

    // workspace layout; eb aliases xb+wt (dead after gemm)
    unsigned short* y  = (unsigned short*)d_ws;            // N*1024 bf16
    unsigned short* eb = y + (size_t)N_NODES * 1024;       // N*1024 bf16
    unsigned short* xb = eb;                               // N*512 bf16 (alias)
    unsigned short* wt = xb + (size_t)N_NODES * FDIM;      // 1024*512 bf16 (alias)
    float* coef = (float*)(eb + (size_t)N_NODES * 1024);   // N*12
    float* sums = coef + (size_t)N_NODES * 12;             // 8*2048
    float* prm  = sums + NCOPY * 2048;                     // 2048

    conv_all<<<5599, 256, 0, stream>>>(x, Wre, Wim, sub_adj, xb, wt, coef, sums);

    // 2560 = 8 rq * 8 col * 40 rg; rows >= 313 exit immediately
    gemm_mfma<<<2560, 256, 0, stream>>>(xb, wt, bre, bim, y);

    evolve_stats<<<N_NODES / 32, 256, 0, stream>>>(y, sub_nodes, coef, eb, sums);

    bnparams_kernel<<<1, 512, 0, stream>>>(sums, gr, br_, gi, bi_, prm);

    finalize_kernel<<<(N_NODES * 64) / 256, 256, 0, stream>>>(x, eb, prm, out);
}